// Round 8
// baseline (478.154 us; speedup 1.0000x reference)
//
#include <hip/hip_runtime.h>

// TopKRouter: N=32768 tokens, D=2048, E=64, K=2.
// R8: transposed, LDS-free, barrier-free. lane = expert (E=64 = wave width).
// w[lane] chunk in VGPRs (per-lane vector loads, L2-resident); x rows are
// wave-uniform -> scalar path (s_load + v_fmac s,v). 8 tokens/wave, 4
// waves/block, grid 1024 (4 blocks/CU, 16 waves/CU). Tail = wave-parallel
// shfl reductions; top-2 tie-break via (value<<6 | 63-lane) u64 keys.

#define NTOK 32768
#define DDIM 2048
#define NEXP 64
#define KB 32             // k-chunk (floats)
#define NCH (DDIM / KB)   // 64
#define TPW 8             // tokens per wave

#define OFF_IDX 0
#define OFF_W 65536
#define OFF_CNT 131072
#define OFF_OVF 131136
#define OFF_ZL 131137
#define OFF_ENT 131138
#define OFF_VAR 131139
#define OFF_CONF 131140

struct RouterWS {
  unsigned int counts[NEXP];
  double z_sum;
  double ent_sum;
};

__global__ __launch_bounds__(256, 4) void router_main(
    const float* __restrict__ x, const float* __restrict__ w,
    float* __restrict__ out, RouterWS* __restrict__ ws) {
  const int tid = threadIdx.x;
  const int lane = tid & 63;                                 // expert id
  const int wv = __builtin_amdgcn_readfirstlane(tid >> 6);   // wave 0..3
  const int tok0 = blockIdx.x * 32 + wv * TPW;               // wave's tokens

  const float* xw = x + (size_t)tok0 * DDIM;      // wave-uniform -> SGPR base
  const float* wrow = w + (size_t)lane * DDIM;    // per-lane expert row

  // w chunk double-buffer in named regs (no runtime-indexed reg arrays)
  float4 wA[8], wB[8];
#pragma unroll
  for (int m = 0; m < 8; ++m) wA[m] = *(const float4*)(wrow + 4 * m);

  float acc[TPW];
#pragma unroll
  for (int t = 0; t < TPW; ++t) acc[t] = 0.f;

  // k ascending: chunk-major, m-major, xyzw — bit-identical logits to R2..R7.
#define STEP(C, WCUR, WNXT)                                                    \
  {                                                                            \
    const int c_ = (C);                                                        \
    if (c_ + 1 < NCH) { /* prefetch next w chunk; vmcnt covers under FMAs */   \
      const float* wn = wrow + (c_ + 1) * KB;                                  \
      _Pragma("unroll") for (int m = 0; m < 8; ++m)                            \
        WNXT[m] = *(const float4*)(wn + 4 * m);                                \
    }                                                                          \
    _Pragma("unroll") for (int m = 0; m < 8; ++m) {                            \
      _Pragma("unroll") for (int t = 0; t < TPW; ++t) { /* 8 indep chains */   \
        float4 xq = *(const float4*)(xw + (size_t)t * DDIM + c_ * KB + 4 * m); \
        float a = acc[t];                                                      \
        a = fmaf(xq.x, WCUR[m].x, a);                                          \
        a = fmaf(xq.y, WCUR[m].y, a);                                          \
        a = fmaf(xq.z, WCUR[m].z, a);                                          \
        a = fmaf(xq.w, WCUR[m].w, a);                                          \
        acc[t] = a;                                                            \
      }                                                                        \
    }                                                                          \
  }

  for (int cc = 0; cc < NCH; cc += 2) {
    STEP(cc, wA, wB);
    STEP(cc + 1, wB, wA);
  }
#undef STEP

  // ---- tail: per token, logits live across the wave's 64 lanes ----
  unsigned int cnt = 0;   // how often this lane's expert was selected
  float zsum = 0.f, esum = 0.f;

#pragma unroll
  for (int t = 0; t < TPW; ++t) {
    float L = acc[t];
    // order-preserving float->uint map (logits finite, keys > 0)
    unsigned int u = __float_as_uint(L);
    u = (u & 0x80000000u) ? ~u : (u | 0x80000000u);
    unsigned long long key =
        ((unsigned long long)u << 6) | (unsigned long long)(63 - lane);

    unsigned long long k1 = key;
#pragma unroll
    for (int o = 32; o > 0; o >>= 1) {
      unsigned long long v = __shfl_xor(k1, o);
      if (v > k1) k1 = v;
    }
    int i1 = 63 - (int)(k1 & 63ull);

    unsigned long long k2 = (lane == i1) ? 0ull : key;
#pragma unroll
    for (int o = 32; o > 0; o >>= 1) {
      unsigned long long v = __shfl_xor(k2, o);
      if (v > k2) k2 = v;
    }
    int i2 = 63 - (int)(k2 & 63ull);

    unsigned int u1 = (unsigned int)(k1 >> 6);
    float m1 = (u1 & 0x80000000u) ? __uint_as_float(u1 & 0x7fffffffu)
                                  : __uint_as_float(~u1);
    unsigned int u2 = (unsigned int)(k2 >> 6);
    float m2v = (u2 & 0x80000000u) ? __uint_as_float(u2 & 0x7fffffffu)
                                   : __uint_as_float(~u2);

    float ex = expf(L - m1);        // lane i1 contributes exp(0) = 1 exactly
    float s = ex;
#pragma unroll
    for (int o = 32; o > 0; o >>= 1) s += __shfl_xor(s, o);

    float p = ex / s;
    float term = -p * logf(p + 1e-10f);
    float ent = term;
#pragma unroll
    for (int o = 32; o > 0; o >>= 1) ent += __shfl_xor(ent, o);

    float p1 = 1.0f / s;            // expf(m1-m1)/s
    float p2 = expf(m2v - m1) / s;
    float wsum = p1 + p2 + 1e-8f;
    float w1 = p1 / wsum;
    float w2 = p2 / wsum;
    float lse = m1 + logf(s);

    zsum += lse;                    // same value in all lanes
    esum += ent;
    cnt += (unsigned int)(lane == i1) + (unsigned int)(lane == i2);

    if (lane == t) {                // lane t stores token t's outputs
      size_t gt = (size_t)tok0 + t;
      out[OFF_IDX + gt * 2 + 0] = (float)i1;
      out[OFF_IDX + gt * 2 + 1] = (float)i2;
      out[OFF_W + gt * 2 + 0] = w1;
      out[OFF_W + gt * 2 + 1] = w2;
      out[OFF_CONF + gt] = fmaxf(w1, w2);
    }
  }

  atomicAdd(&ws->counts[lane], cnt);          // one wave-instr, 64 counters
  if (lane == 0) {
    atomicAdd(&ws->z_sum, (double)zsum);
    atomicAdd(&ws->ent_sum, (double)esum);
  }
}

__global__ void router_final(float* __restrict__ out, RouterWS* __restrict__ ws) {
  int e = threadIdx.x;  // 64 threads
  float c = (float)ws->counts[e];
  out[OFF_CNT + e] = c;
  float over = fmaxf(c - 1280.f, 0.f);   // capacity = int(1.25*32768/64*2)
  float ld = c / 65536.f - (1.f / 64.f);
  float so = over, sv = ld * ld;
#pragma unroll
  for (int o = 32; o > 0; o >>= 1) {
    so += __shfl_down(so, o);
    sv += __shfl_down(sv, o);
  }
  if (e == 0) {
    out[OFF_OVF] = so / 32768.f * 100.f;
    out[OFF_VAR] = sv / 64.f;
    out[OFF_ZL] = (float)(ws->z_sum / 32768.0 * 0.01);
    out[OFF_ENT] = (float)(ws->ent_sum / 32768.0);
  }
}

extern "C" void kernel_launch(void* const* d_in, const int* in_sizes, int n_in,
                              void* d_out, int out_size, void* d_ws, size_t ws_size,
                              hipStream_t stream) {
  const float* x = (const float*)d_in[0];   // hidden_states [4,8192,2048] f32
  const float* w = (const float*)d_in[1];   // gate_weight [64,2048] f32
  float* out = (float*)d_out;
  RouterWS* ws = (RouterWS*)d_ws;

  (void)hipMemsetAsync(d_ws, 0, sizeof(RouterWS), stream);
  hipLaunchKernelGGL(router_main, dim3(NTOK / 32), dim3(256), 0, stream,
                     x, w, out, ws);
  hipLaunchKernelGGL(router_final, dim3(1), dim3(64), 0, stream, out, ws);
}

// Round 9
// 359.409 us; speedup vs baseline: 1.3304x; 1.3304x over previous
//
#include <hip/hip_runtime.h>

// TopKRouter: N=32768 tokens, D=2048, E=64, K=2.
// R9 = R2's floor-VALU datapath (lane=token, 16 experts/wave serially-uniform,
// KB=32, e-outer/m-inner) + explicit e-ping-pong w prefetch (kills the
// serial s_load latency chain) + async global_load_lds x staging with
// pre-swizzled global source (linear LDS dest, coalesced, 1 barrier/chunk).

#define NTOK 32768
#define DDIM 2048
#define NEXP 64
#define TTILE 64          // tokens per block
#define KB 32             // k-chunk (floats)
#define NCH (DDIM / KB)   // 64
#define STG 2048          // floats per stage buffer (64 rows * 32)
#define LG_STRIDE 68      // 64 + 4 pad for logit tail

#define OFF_IDX 0
#define OFF_W 65536
#define OFF_CNT 131072
#define OFF_OVF 131136
#define OFF_ZL 131137
#define OFF_ENT 131138
#define OFF_VAR 131139
#define OFF_CONF 131140

struct RouterWS {
  unsigned int counts[NEXP];
  double z_sum;
  double ent_sum;
};

typedef __attribute__((address_space(1))) void v1_t;
typedef __attribute__((address_space(3))) void v3_t;

__device__ __forceinline__ void cp16(const float* g, float* l) {
  __builtin_amdgcn_global_load_lds((v1_t*)g, (v3_t*)l, 16, 0, 0);
}

__global__ __launch_bounds__(256, 2) void router_main(
    const float* __restrict__ x, const float* __restrict__ w,
    float* __restrict__ out, RouterWS* __restrict__ ws) {
  // [0,2048) x buf0 | [2048,4096) x buf1 ; logit tile [0,64*68) aliases after
  // the final K-loop barrier. 4352 floats = 17.4 KB.
  __shared__ float smem[TTILE * LG_STRIDE];
  __shared__ unsigned int hist[NEXP];

  const int tid = threadIdx.x;                              // 0..255
  const int L = tid & 63;                                   // lane = token
  const int wv = __builtin_amdgcn_readfirstlane(tid >> 6);  // expert grp 0..3
  const int sw = L & 7;                                     // read swizzle key

  const float* xg = x + (size_t)blockIdx.x * TTILE * DDIM;

  // Staging slots: slot i holds x[row=i>>3][col4 = (i&7)^(row&7)] — the
  // column permutation stays inside each row's 128B segment (coalesced), and
  // LDS dest is LINEAR (slot i at float-offset 4i), as global_load_lds needs.
  // Thread stages slots tid (rows 0..31) and tid+256 (rows 32..63).
  const int r0 = tid >> 3;
  const int j0 = (tid & 7) ^ (r0 & 7);   // (r0+32)&7 == r0&7, same column
  const size_t g0 = (size_t)r0 * DDIM + 4 * j0;
  const size_t g1 = (size_t)(r0 + 32) * DDIM + 4 * j0;
  const int l0 = tid * 4;
  const int l1 = (tid + 256) * 4;

  // Prefetch chunk 0 into buf0.
  cp16(xg + g0, &smem[l0]);
  cp16(xg + g1, &smem[l1]);

  float acc[16];
#pragma unroll
  for (int e = 0; e < 16; ++e) acc[e] = 0.f;

  const float* wbase = w + (size_t)wv * 16 * DDIM;  // uniform -> scalar path

  __syncthreads();  // drains vmcnt before first use

#define FMA8(A, XR, WQ)                                                        \
  _Pragma("unroll") for (int m = 0; m < 8; ++m) {                              \
    A = fmaf(XR[m].x, WQ[m].x, A);                                            \
    A = fmaf(XR[m].y, WQ[m].y, A);                                            \
    A = fmaf(XR[m].z, WQ[m].z, A);                                            \
    A = fmaf(XR[m].w, WQ[m].w, A);                                            \
  }

#define STEP(C, CB, NB)                                                        \
  {                                                                            \
    const int c_ = (C);                                                        \
    if (c_ + 1 < NCH) { /* async stage next chunk; drains at end barrier */    \
      const size_t k0 = (size_t)(c_ + 1) * KB;                                 \
      cp16(xg + g0 + k0, &smem[(NB) + l0]);                                    \
      cp16(xg + g1 + k0, &smem[(NB) + l1]);                                    \
    }                                                                          \
    const float* wc = wbase + c_ * KB;                                         \
    float4 wqA[8], wqB[8];                                                     \
    _Pragma("unroll") for (int m = 0; m < 8; ++m)                              \
      wqA[m] = ((const float4*)wc)[m]; /* e=0 */                               \
    float4 xr[8];  /* my token's swizzled row: true col m at slot m^sw */      \
    _Pragma("unroll") for (int m = 0; m < 8; ++m)                              \
      xr[m] = *(const float4*)&smem[(CB) + L * 32 + 4 * (m ^ sw)];             \
    _Pragma("unroll") for (int ep = 0; ep < 8; ++ep) { /* e ping-pong pairs */ \
      const int e0 = 2 * ep;                                                   \
      _Pragma("unroll") for (int m = 0; m < 8; ++m)                            \
        wqB[m] = ((const float4*)(wc + (size_t)(e0 + 1) * DDIM))[m];           \
      float a0 = acc[e0];                                                      \
      FMA8(a0, xr, wqA);                                                       \
      acc[e0] = a0;                                                            \
      if (e0 + 2 < 16) {                                                       \
        _Pragma("unroll") for (int m = 0; m < 8; ++m)                          \
          wqA[m] = ((const float4*)(wc + (size_t)(e0 + 2) * DDIM))[m];         \
      }                                                                        \
      float a1 = acc[e0 + 1];                                                  \
      FMA8(a1, xr, wqB);                                                       \
      acc[e0 + 1] = a1;                                                        \
    }                                                                          \
    __syncthreads();                                                           \
  }

  for (int cc = 0; cc < NCH; cc += 2) {
    STEP(cc, 0, STG);     // compile-time buffer bases
    STEP(cc + 1, STG, 0);
  }
#undef STEP
#undef FMA8

  // logits -> lg[token][expert], stride 68
#pragma unroll
  for (int e = 0; e < 16; ++e) smem[L * LG_STRIDE + wv * 16 + e] = acc[e];
  if (tid < NEXP) hist[tid] = 0;
  __syncthreads();

  if (tid < NEXP) {  // wave 0: one token per lane, serial over 64 experts
    const int t = tid;
    const float* Lg = &smem[t * LG_STRIDE];

    float m1 = Lg[0];
    int i1 = 0;
    for (int e = 1; e < NEXP; ++e) {
      float v = Lg[e];
      if (v > m1) { m1 = v; i1 = e; }  // strict > keeps lowest index on ties
    }
    float m2 = -3.4e38f;
    int i2 = 0;
    for (int e = 0; e < NEXP; ++e) {
      if (e == i1) continue;
      float v = Lg[e];
      if (v > m2) { m2 = v; i2 = e; }
    }

    float s = 0.f;
    for (int e = 0; e < NEXP; ++e) s += expf(Lg[e] - m1);
    float p1 = expf(Lg[i1] - m1) / s;
    float p2 = expf(Lg[i2] - m1) / s;
    float wsum = p1 + p2 + 1e-8f;
    float w1 = p1 / wsum;
    float w2 = p2 / wsum;

    float ent = 0.f;
    for (int e = 0; e < NEXP; ++e) {
      float p = expf(Lg[e] - m1) / s;
      ent -= p * logf(p + 1e-10f);
    }
    float lse = m1 + logf(s);

    size_t gt = (size_t)blockIdx.x * TTILE + t;
    out[OFF_IDX + gt * 2 + 0] = (float)i1;
    out[OFF_IDX + gt * 2 + 1] = (float)i2;
    out[OFF_W + gt * 2 + 0] = w1;
    out[OFF_W + gt * 2 + 1] = w2;
    out[OFF_CONF + gt] = fmaxf(w1, w2);

    atomicAdd(&hist[i1], 1u);
    atomicAdd(&hist[i2], 1u);

    float zv = lse, ev = ent;
#pragma unroll
    for (int o = 32; o > 0; o >>= 1) {
      zv += __shfl_down(zv, o);
      ev += __shfl_down(ev, o);
    }
    if (t == 0) {
      atomicAdd(&ws->z_sum, (double)zv);
      atomicAdd(&ws->ent_sum, (double)ev);
    }
  }
  __syncthreads();
  if (tid < NEXP) atomicAdd(&ws->counts[tid], hist[tid]);
}

__global__ void router_final(float* __restrict__ out, RouterWS* __restrict__ ws) {
  int e = threadIdx.x;  // 64 threads
  float c = (float)ws->counts[e];
  out[OFF_CNT + e] = c;
  float over = fmaxf(c - 1280.f, 0.f);   // capacity = int(1.25*32768/64*2)
  float ld = c / 65536.f - (1.f / 64.f);
  float so = over, sv = ld * ld;
#pragma unroll
  for (int o = 32; o > 0; o >>= 1) {
    so += __shfl_down(so, o);
    sv += __shfl_down(sv, o);
  }
  if (e == 0) {
    out[OFF_OVF] = so / 32768.f * 100.f;
    out[OFF_VAR] = sv / 64.f;
    out[OFF_ZL] = (float)(ws->z_sum / 32768.0 * 0.01);
    out[OFF_ENT] = (float)(ws->ent_sum / 32768.0);
  }
}

extern "C" void kernel_launch(void* const* d_in, const int* in_sizes, int n_in,
                              void* d_out, int out_size, void* d_ws, size_t ws_size,
                              hipStream_t stream) {
  const float* x = (const float*)d_in[0];   // hidden_states [4,8192,2048] f32
  const float* w = (const float*)d_in[1];   // gate_weight [64,2048] f32
  float* out = (float*)d_out;
  RouterWS* ws = (RouterWS*)d_ws;

  (void)hipMemsetAsync(d_ws, 0, sizeof(RouterWS), stream);
  hipLaunchKernelGGL(router_main, dim3(NTOK / TTILE), dim3(256), 0, stream,
                     x, w, out, ws);
  hipLaunchKernelGGL(router_final, dim3(1), dim3(64), 0, stream, out, ws);
}

// Round 10
// 250.896 us; speedup vs baseline: 1.9058x; 1.4325x over previous
//
#include <hip/hip_runtime.h>

// TopKRouter: N=32768 tokens, D=2048, E=64, K=2.
// R10 = R5 (best clean datapath: w broadcast from LDS, reg-staged dbuf,
// pad-36) amortized 2x: 2 tokens/lane (TTILE=128) and 2 blocks/CU.

#define NTOK 32768
#define DDIM 2048
#define NEXP 64
#define TTILE 128          // tokens per block (2 per lane)
#define KB 32              // k-chunk (floats)
#define NCH (DDIM / KB)    // 64
#define XSTR 36            // 32 + 4 pad
#define XBUF (TTILE * XSTR)       // 4608 floats per x buffer
#define WBUF (NEXP * XSTR)        // 2304 floats per w buffer
#define WOFF (2 * XBUF)           // 9216: w buffers start
#define LG_STRIDE 68       // 64 + 4 pad for logit tail

#define OFF_IDX 0
#define OFF_W 65536
#define OFF_CNT 131072
#define OFF_OVF 131136
#define OFF_ZL 131137
#define OFF_ENT 131138
#define OFF_VAR 131139
#define OFF_CONF 131140

struct RouterWS {
  unsigned int counts[NEXP];
  double z_sum;
  double ent_sum;
};

__global__ __launch_bounds__(512, 4) void router_main(
    const float* __restrict__ x, const float* __restrict__ w,
    float* __restrict__ out, RouterWS* __restrict__ ws) {
  // [0,4608) x buf0 | [4608,9216) x buf1 | [9216,11520) w buf0 |
  // [11520,13824) w buf1. Logit tile 128*68=8704 floats aliases the front
  // after the final K-loop barrier. 13824 floats = 55.3 KB -> 2 blocks/CU.
  __shared__ float smem[2 * XBUF + 2 * WBUF];
  __shared__ unsigned int hist[NEXP];

  const int tid = threadIdx.x;                              // 0..511
  const int L = tid & 63;                                   // lane
  const int wv = __builtin_amdgcn_readfirstlane(tid >> 6);  // expert grp 0..7

  const float* xg = x + (size_t)blockIdx.x * TTILE * DDIM;

  // staging map: sr = row 0..63, sc = float col; thread stages x rows sr and
  // sr+64 plus w row sr (one float4 each).
  const int sr = tid >> 3;
  const int sc = (tid & 7) * 4;

  // Prefetch chunk 0.
  float4 rx0 = *(const float4*)(xg + (size_t)sr * DDIM + sc);
  float4 rx1 = *(const float4*)(xg + (size_t)(sr + 64) * DDIM + sc);
  float4 rw = *(const float4*)(w + (size_t)sr * DDIM + sc);
  *(float4*)&smem[sr * XSTR + sc] = rx0;
  *(float4*)&smem[(sr + 64) * XSTR + sc] = rx1;
  *(float4*)&smem[WOFF + sr * XSTR + sc] = rw;

  float acc0[8], acc1[8];
#pragma unroll
  for (int e = 0; e < 8; ++e) { acc0[e] = 0.f; acc1[e] = 0.f; }

  __syncthreads();

  for (int c = 0; c < NCH; ++c) {
    const int cxb = (c & 1) * XBUF;
    const int cwb = WOFF + (c & 1) * WBUF;

    if (c + 1 < NCH) {  // issue next chunk's globals; return under FMAs
      int k0 = (c + 1) * KB;
      rx0 = *(const float4*)(xg + (size_t)sr * DDIM + k0 + sc);
      rx1 = *(const float4*)(xg + (size_t)(sr + 64) * DDIM + k0 + sc);
      rw = *(const float4*)(w + (size_t)sr * DDIM + k0 + sc);
    }

    // my two tokens' 32 x-values each -> VGPRs (16 ds_read_b128)
    float4 xr0[8], xr1[8];
#pragma unroll
    for (int m = 0; m < 8; ++m) {
      xr0[m] = *(const float4*)&smem[cxb + L * XSTR + 4 * m];
      xr1[m] = *(const float4*)&smem[cxb + (L + 64) * XSTR + 4 * m];
    }

#pragma unroll
    for (int e = 0; e < 8; ++e) {
      // uniform address across the wave -> LDS broadcast, no conflicts
      const float* wrow = &smem[cwb + (8 * wv + e) * XSTR];
      float a0 = acc0[e], a1 = acc1[e];
#pragma unroll
      for (int m = 0; m < 8; ++m) {
        float4 wq = *(const float4*)&wrow[4 * m];
        a0 = fmaf(xr0[m].x, wq.x, a0);
        a0 = fmaf(xr0[m].y, wq.y, a0);
        a0 = fmaf(xr0[m].z, wq.z, a0);
        a0 = fmaf(xr0[m].w, wq.w, a0);
        a1 = fmaf(xr1[m].x, wq.x, a1);
        a1 = fmaf(xr1[m].y, wq.y, a1);
        a1 = fmaf(xr1[m].z, wq.z, a1);
        a1 = fmaf(xr1[m].w, wq.w, a1);
      }
      acc0[e] = a0;
      acc1[e] = a1;
    }

    if (c + 1 < NCH) {  // loads returned; stage next buffers
      const int nxb = ((c + 1) & 1) * XBUF;
      const int nwb = WOFF + ((c + 1) & 1) * WBUF;
      *(float4*)&smem[nxb + sr * XSTR + sc] = rx0;
      *(float4*)&smem[nxb + (sr + 64) * XSTR + sc] = rx1;
      *(float4*)&smem[nwb + sr * XSTR + sc] = rw;
    }
    __syncthreads();
  }

  // logits -> lg[token][expert], stride 68 (aliases x buffers)
#pragma unroll
  for (int e = 0; e < 8; ++e) {
    smem[L * LG_STRIDE + wv * 8 + e] = acc0[e];
    smem[(L + 64) * LG_STRIDE + wv * 8 + e] = acc1[e];
  }
  if (tid < NEXP) hist[tid] = 0;
  __syncthreads();

  if (tid < TTILE) {  // waves 0-1: one token per lane, serial over 64 experts
    const int t = tid;
    const float* Lg = &smem[t * LG_STRIDE];

    float m1 = Lg[0];
    int i1 = 0;
    for (int e = 1; e < NEXP; ++e) {
      float v = Lg[e];
      if (v > m1) { m1 = v; i1 = e; }  // strict > keeps lowest index on ties
    }
    float m2 = -3.4e38f;
    int i2 = 0;
    for (int e = 0; e < NEXP; ++e) {
      if (e == i1) continue;
      float v = Lg[e];
      if (v > m2) { m2 = v; i2 = e; }
    }

    float s = 0.f;
    for (int e = 0; e < NEXP; ++e) s += expf(Lg[e] - m1);
    float p1 = expf(Lg[i1] - m1) / s;
    float p2 = expf(Lg[i2] - m1) / s;
    float wsum = p1 + p2 + 1e-8f;
    float w1 = p1 / wsum;
    float w2 = p2 / wsum;

    float ent = 0.f;
    for (int e = 0; e < NEXP; ++e) {
      float p = expf(Lg[e] - m1) / s;
      ent -= p * logf(p + 1e-10f);
    }
    float lse = m1 + logf(s);

    size_t gt = (size_t)blockIdx.x * TTILE + t;
    out[OFF_IDX + gt * 2 + 0] = (float)i1;
    out[OFF_IDX + gt * 2 + 1] = (float)i2;
    out[OFF_W + gt * 2 + 0] = w1;
    out[OFF_W + gt * 2 + 1] = w2;
    out[OFF_CONF + gt] = fmaxf(w1, w2);

    atomicAdd(&hist[i1], 1u);
    atomicAdd(&hist[i2], 1u);

    float zv = lse, ev = ent;
#pragma unroll
    for (int o = 32; o > 0; o >>= 1) {
      zv += __shfl_down(zv, o);
      ev += __shfl_down(ev, o);
    }
    if ((tid & 63) == 0) {  // one atomic per participating wave
      atomicAdd(&ws->z_sum, (double)zv);
      atomicAdd(&ws->ent_sum, (double)ev);
    }
  }
  __syncthreads();
  if (tid < NEXP) atomicAdd(&ws->counts[tid], hist[tid]);
}

__global__ void router_final(float* __restrict__ out, RouterWS* __restrict__ ws) {
  int e = threadIdx.x;  // 64 threads
  float c = (float)ws->counts[e];
  out[OFF_CNT + e] = c;
  float over = fmaxf(c - 1280.f, 0.f);   // capacity = int(1.25*32768/64*2)
  float ld = c / 65536.f - (1.f / 64.f);
  float so = over, sv = ld * ld;
#pragma unroll
  for (int o = 32; o > 0; o >>= 1) {
    so += __shfl_down(so, o);
    sv += __shfl_down(sv, o);
  }
  if (e == 0) {
    out[OFF_OVF] = so / 32768.f * 100.f;
    out[OFF_VAR] = sv / 64.f;
    out[OFF_ZL] = (float)(ws->z_sum / 32768.0 * 0.01);
    out[OFF_ENT] = (float)(ws->ent_sum / 32768.0);
  }
}

extern "C" void kernel_launch(void* const* d_in, const int* in_sizes, int n_in,
                              void* d_out, int out_size, void* d_ws, size_t ws_size,
                              hipStream_t stream) {
  const float* x = (const float*)d_in[0];   // hidden_states [4,8192,2048] f32
  const float* w = (const float*)d_in[1];   // gate_weight [64,2048] f32
  float* out = (float*)d_out;
  RouterWS* ws = (RouterWS*)d_ws;

  (void)hipMemsetAsync(d_ws, 0, sizeof(RouterWS), stream);
  hipLaunchKernelGGL(router_main, dim3(NTOK / TTILE), dim3(512), 0, stream,
                     x, w, out, ws);
  hipLaunchKernelGGL(router_final, dim3(1), dim3(64), 0, stream, out, ws);
}